// Round 2
// baseline (9791.741 us; speedup 1.0000x reference)
//
#include <hip/hip_runtime.h>

// Attention2: point-cloud attention, N=1M, KNN=9, C_in=C_inner=20, REPEAT=2.
// All data fp32. Three training-mode BNs require global stats passes.
// R2: kill VGPR spill in k3/k4 (unroll-1 neighbor loop, launch_bounds(256,4),
//     preloaded contiguous index/weight vectors).

constexpr int KNN_ = 9;
constexpr int CI   = 20;   // in/inner channels
constexpr int CC   = 23;   // CI + 3 (xyz)
constexpr int CAT  = 40;   // CI + CI
constexpr float EPS = 1e-5f;

// ---- block-wide reduce of CNT float partials into f64 global accumulators ----
template <int CNT>
__device__ inline void block_reduce_add(float (&v)[CNT], double* __restrict__ dst,
                                        float* __restrict__ lds /*4*CNT floats*/) {
    const int lane = threadIdx.x & 63;
    const int wid  = threadIdx.x >> 6;
#pragma unroll
    for (int i = 0; i < CNT; ++i) {
        float x = v[i];
#pragma unroll
        for (int off = 32; off > 0; off >>= 1) x += __shfl_down(x, off);
        if (lane == 0) lds[wid * CNT + i] = x;
    }
    __syncthreads();
    if (threadIdx.x < CNT) {
        float x = lds[threadIdx.x] + lds[CNT + threadIdx.x] +
                  lds[2 * CNT + threadIdx.x] + lds[3 * CNT + threadIdx.x];
        atomicAdd(dst + threadIdx.x, (double)x);
    }
}

__device__ inline void load_row20(const float* __restrict__ p, float (&v)[CC]) {
    const float4* f = reinterpret_cast<const float4*>(p);
    const float4 f0 = f[0], f1 = f[1], f2 = f[2], f3 = f[3], f4 = f[4];
    v[0]=f0.x; v[1]=f0.y; v[2]=f0.z; v[3]=f0.w;
    v[4]=f1.x; v[5]=f1.y; v[6]=f1.z; v[7]=f1.w;
    v[8]=f2.x; v[9]=f2.y; v[10]=f2.z; v[11]=f2.w;
    v[12]=f3.x; v[13]=f3.y; v[14]=f3.z; v[15]=f3.w;
    v[16]=f4.x; v[17]=f4.y; v[18]=f4.z; v[19]=f4.w;
}

// ---- K1: per-channel sum/sumsq of conv1 output over all (n,k) — BN1 stats ----
__global__ __launch_bounds__(256, 4) void k1_stats(
    const float* __restrict__ points, const float* __restrict__ feature,
    const int* __restrict__ index, const float* __restrict__ W1,
    double* __restrict__ stats, int N)
{
    __shared__ float Ws[CI * CC];
    __shared__ float red[4 * 2 * CI];
    for (int i = threadIdx.x; i < CI * CC; i += 256) Ws[i] = W1[i];
    __syncthreads();

    float acc[2 * CI];
#pragma unroll
    for (int i = 0; i < 2 * CI; ++i) acc[i] = 0.f;

    const int total = N * KNN_;
#pragma unroll 1
    for (int pid = blockIdx.x * 256 + threadIdx.x; pid < total; pid += gridDim.x * 256) {
        const int n = pid / KNN_;
        const int j = index[pid];
        float in[CC];
        load_row20(feature + (size_t)j * CI, in);
        in[20] = points[3*j+0] - points[3*n+0];
        in[21] = points[3*j+1] - points[3*n+1];
        in[22] = points[3*j+2] - points[3*n+2];
#pragma unroll
        for (int o = 0; o < CI; ++o) {
            float y = 0.f;
#pragma unroll
            for (int c = 0; c < CC; ++c) y = fmaf(Ws[o * CC + c], in[c], y);
            acc[o] += y;
            acc[CI + o] = fmaf(y, y, acc[CI + o]);
        }
    }
    __syncthreads();
    block_reduce_add<2 * CI>(acc, stats, red);
}

// ---- K3: recompute conv1, apply BN1, attention weights w, aggregate xagg ----
__global__ __launch_bounds__(256, 4) void k3_attn(
    const float* __restrict__ points, const float* __restrict__ feature,
    const int* __restrict__ index, const float* __restrict__ W1,
    const float* __restrict__ g1, const float* __restrict__ b1,
    const double* __restrict__ stats,
    float* __restrict__ wbuf, float* __restrict__ xagg, int N)
{
    __shared__ float Ws[CI * CC];
    __shared__ float sc[CI], sh[CI];
    for (int i = threadIdx.x; i < CI * CC; i += 256) Ws[i] = W1[i];
    if (threadIdx.x < CI) {
        const double M = (double)N * KNN_;
        const double mean = stats[threadIdx.x] / M;
        const double var  = stats[CI + threadIdx.x] / M - mean * mean;
        const float s = g1[threadIdx.x] * rsqrtf((float)var + EPS);
        sc[threadIdx.x] = s;
        sh[threadIdx.x] = b1[threadIdx.x] - (float)mean * s;
    }
    __syncthreads();

    const int n = blockIdx.x * 256 + threadIdx.x;
    if (n >= N) return;

    int idx[KNN_];
#pragma unroll
    for (int k = 0; k < KNN_; ++k) idx[k] = index[n * KNN_ + k];

    const float pnx = points[3*n], pny = points[3*n+1], pnz = points[3*n+2];
    float x0[CI], accv[CI];
#pragma unroll
    for (int o = 0; o < CI; ++o) accv[o] = 0.f;

#pragma unroll 1
    for (int k = 0; k < KNN_; ++k) {
        const int j = idx[k];
        float in[CC];
        load_row20(feature + (size_t)j * CI, in);
        in[20] = points[3*j+0] - pnx;
        in[21] = points[3*j+1] - pny;
        in[22] = points[3*j+2] - pnz;
        float xk[CI];
#pragma unroll
        for (int o = 0; o < CI; ++o) {
            float y = 0.f;
#pragma unroll
            for (int c = 0; c < CC; ++c) y = fmaf(Ws[o * CC + c], in[c], y);
            xk[o] = fmaf(y, sc[o], sh[o]);
        }
        if (k == 0) {
#pragma unroll
            for (int o = 0; o < CI; ++o) x0[o] = xk[o];
        }
        float w = 0.f;
#pragma unroll
        for (int o = 0; o < CI; ++o) w = fmaf(xk[o], x0[o], w);
        wbuf[n * KNN_ + k] = w;
#pragma unroll
        for (int o = 0; o < CI; ++o) accv[o] = fmaf(xk[o], w, accv[o]);
    }
    float4* xo = reinterpret_cast<float4*>(xagg + (size_t)n * CI);
    xo[0] = make_float4(accv[0],  accv[1],  accv[2],  accv[3]);
    xo[1] = make_float4(accv[4],  accv[5],  accv[6],  accv[7]);
    xo[2] = make_float4(accv[8],  accv[9],  accv[10], accv[11]);
    xo[3] = make_float4(accv[12], accv[13], accv[14], accv[15]);
    xo[4] = make_float4(accv[16], accv[17], accv[18], accv[19]);
}

// ---- K4: x2[n] = sum_k xagg[idx[n,k]]*w[n,k]; fused BN2 stats ----
__global__ __launch_bounds__(256, 4) void k4_prop(
    const int* __restrict__ index, const float* __restrict__ wbuf,
    const float* __restrict__ xagg, float* __restrict__ x2,
    double* __restrict__ stats2, int N)
{
    __shared__ float red[4 * 2 * CI];
    float st[2 * CI];
#pragma unroll
    for (int i = 0; i < 2 * CI; ++i) st[i] = 0.f;

#pragma unroll 1
    for (int n = blockIdx.x * 256 + threadIdx.x; n < N; n += gridDim.x * 256) {
        int idx[KNN_];
        float wk[KNN_];
#pragma unroll
        for (int k = 0; k < KNN_; ++k) idx[k] = index[n * KNN_ + k];
#pragma unroll
        for (int k = 0; k < KNN_; ++k) wk[k] = wbuf[n * KNN_ + k];

        float accv[CI];
#pragma unroll
        for (int o = 0; o < CI; ++o) accv[o] = 0.f;
#pragma unroll 1
        for (int k = 0; k < KNN_; ++k) {
            const int j = idx[k];
            const float w = wk[k];
            float gv[CC];
            load_row20(xagg + (size_t)j * CI, gv);
#pragma unroll
            for (int o = 0; o < CI; ++o) accv[o] = fmaf(gv[o], w, accv[o]);
        }
        float4* xo = reinterpret_cast<float4*>(x2 + (size_t)n * CI);
        xo[0] = make_float4(accv[0],  accv[1],  accv[2],  accv[3]);
        xo[1] = make_float4(accv[4],  accv[5],  accv[6],  accv[7]);
        xo[2] = make_float4(accv[8],  accv[9],  accv[10], accv[11]);
        xo[3] = make_float4(accv[12], accv[13], accv[14], accv[15]);
        xo[4] = make_float4(accv[16], accv[17], accv[18], accv[19]);
#pragma unroll
        for (int o = 0; o < CI; ++o) {
            st[o] += accv[o];
            st[CI + o] = fmaf(accv[o], accv[o], st[CI + o]);
        }
    }
    __syncthreads();
    block_reduce_add<2 * CI>(st, stats2, red);
}

// ---- K6: h=relu(bn2(x2)); cat=[h,feature]; y=Wr1@cat+br1; fused BN3 stats ----
__global__ __launch_bounds__(256) void k6_refine1(
    const float* __restrict__ x2, const float* __restrict__ feature,
    const float* __restrict__ g2, const float* __restrict__ b2,
    const float* __restrict__ Wr1, const float* __restrict__ br1,
    const double* __restrict__ stats2,
    float* __restrict__ ybuf, double* __restrict__ stats3, int N)
{
    __shared__ float Ws[CI * CAT];
    __shared__ float sc[CI], sh[CI];
    __shared__ float red[4 * 2 * CI];
    for (int i = threadIdx.x; i < CI * CAT; i += 256) Ws[i] = Wr1[i];
    if (threadIdx.x < CI) {
        const double M = (double)N;
        const double mean = stats2[threadIdx.x] / M;
        const double var  = stats2[CI + threadIdx.x] / M - mean * mean;
        const float s = g2[threadIdx.x] * rsqrtf((float)var + EPS);
        sc[threadIdx.x] = s;
        sh[threadIdx.x] = b2[threadIdx.x] - (float)mean * s;
    }
    __syncthreads();

    float st[2 * CI];
#pragma unroll
    for (int i = 0; i < 2 * CI; ++i) st[i] = 0.f;

#pragma unroll 1
    for (int n = blockIdx.x * 256 + threadIdx.x; n < N; n += gridDim.x * 256) {
        float cat[CAT];
        const float4* xi = reinterpret_cast<const float4*>(x2 + (size_t)n * CI);
#pragma unroll
        for (int q = 0; q < 5; ++q) {
            const float4 v = xi[q];
            cat[4*q+0] = fmaxf(fmaf(v.x, sc[4*q+0], sh[4*q+0]), 0.f);
            cat[4*q+1] = fmaxf(fmaf(v.y, sc[4*q+1], sh[4*q+1]), 0.f);
            cat[4*q+2] = fmaxf(fmaf(v.z, sc[4*q+2], sh[4*q+2]), 0.f);
            cat[4*q+3] = fmaxf(fmaf(v.w, sc[4*q+3], sh[4*q+3]), 0.f);
        }
        const float4* fi = reinterpret_cast<const float4*>(feature + (size_t)n * CI);
#pragma unroll
        for (int q = 0; q < 5; ++q) {
            const float4 v = fi[q];
            cat[CI+4*q+0] = v.x; cat[CI+4*q+1] = v.y;
            cat[CI+4*q+2] = v.z; cat[CI+4*q+3] = v.w;
        }
        float yv[CI];
#pragma unroll
        for (int o = 0; o < CI; ++o) {
            float y = br1[o];
#pragma unroll
            for (int c = 0; c < CAT; ++c) y = fmaf(Ws[o * CAT + c], cat[c], y);
            yv[o] = y;
            st[o] += y;
            st[CI + o] = fmaf(y, y, st[CI + o]);
        }
        float4* yo = reinterpret_cast<float4*>(ybuf + (size_t)n * CI);
        yo[0] = make_float4(yv[0],  yv[1],  yv[2],  yv[3]);
        yo[1] = make_float4(yv[4],  yv[5],  yv[6],  yv[7]);
        yo[2] = make_float4(yv[8],  yv[9],  yv[10], yv[11]);
        yo[3] = make_float4(yv[12], yv[13], yv[14], yv[15]);
        yo[4] = make_float4(yv[16], yv[17], yv[18], yv[19]);
    }
    __syncthreads();
    block_reduce_add<2 * CI>(st, stats3, red);
}

// ---- K8: out = relu(bn3(y)) @ Wr2.T + br2 ----
__global__ __launch_bounds__(256) void k8_out(
    const float* __restrict__ ybuf,
    const float* __restrict__ g3, const float* __restrict__ b3,
    const float* __restrict__ Wr2, const float* __restrict__ br2,
    const double* __restrict__ stats3, float* __restrict__ out, int N)
{
    __shared__ float Ws[CI * CI];
    __shared__ float sc[CI], sh[CI];
    for (int i = threadIdx.x; i < CI * CI; i += 256) Ws[i] = Wr2[i];
    if (threadIdx.x < CI) {
        const double M = (double)N;
        const double mean = stats3[threadIdx.x] / M;
        const double var  = stats3[CI + threadIdx.x] / M - mean * mean;
        const float s = g3[threadIdx.x] * rsqrtf((float)var + EPS);
        sc[threadIdx.x] = s;
        sh[threadIdx.x] = b3[threadIdx.x] - (float)mean * s;
    }
    __syncthreads();

    const int n = blockIdx.x * 256 + threadIdx.x;
    if (n >= N) return;

    float z[CI];
    const float4* yi = reinterpret_cast<const float4*>(ybuf + (size_t)n * CI);
#pragma unroll
    for (int q = 0; q < 5; ++q) {
        const float4 v = yi[q];
        z[4*q+0] = fmaxf(fmaf(v.x, sc[4*q+0], sh[4*q+0]), 0.f);
        z[4*q+1] = fmaxf(fmaf(v.y, sc[4*q+1], sh[4*q+1]), 0.f);
        z[4*q+2] = fmaxf(fmaf(v.z, sc[4*q+2], sh[4*q+2]), 0.f);
        z[4*q+3] = fmaxf(fmaf(v.w, sc[4*q+3], sh[4*q+3]), 0.f);
    }
    float ov[CI];
#pragma unroll
    for (int o = 0; o < CI; ++o) {
        float y = br2[o];
#pragma unroll
        for (int c = 0; c < CI; ++c) y = fmaf(Ws[o * CI + c], z[c], y);
        ov[o] = y;
    }
    float4* oo = reinterpret_cast<float4*>(out + (size_t)n * CI);
    oo[0] = make_float4(ov[0],  ov[1],  ov[2],  ov[3]);
    oo[1] = make_float4(ov[4],  ov[5],  ov[6],  ov[7]);
    oo[2] = make_float4(ov[8],  ov[9],  ov[10], ov[11]);
    oo[3] = make_float4(ov[12], ov[13], ov[14], ov[15]);
    oo[4] = make_float4(ov[16], ov[17], ov[18], ov[19]);
}

extern "C" void kernel_launch(void* const* d_in, const int* in_sizes, int n_in,
                              void* d_out, int out_size, void* d_ws, size_t ws_size,
                              hipStream_t stream) {
    const float* points  = (const float*)d_in[0];
    const float* feature = (const float*)d_in[1];
    const int*   index   = (const int*)  d_in[2];
    const float* W1      = (const float*)d_in[3];
    const float* g1      = (const float*)d_in[4];
    const float* b1      = (const float*)d_in[5];
    const float* g2      = (const float*)d_in[6];
    const float* b2      = (const float*)d_in[7];
    const float* Wr1     = (const float*)d_in[8];
    const float* br1     = (const float*)d_in[9];
    const float* g3      = (const float*)d_in[10];
    const float* b3      = (const float*)d_in[11];
    const float* Wr2     = (const float*)d_in[12];
    const float* br2     = (const float*)d_in[13];
    const int N = in_sizes[0] / 3;
    float* out = (float*)d_out;

    // workspace layout: [stats: 120 doubles, padded to 1KB][w: N*9 f32][xagg: N*20 f32][x2: N*20 f32]
    // ybuf aliases xagg (dead after k4). Total ~196 MB.
    double* stats = (double*)d_ws;
    char* base = (char*)d_ws;
    float* wbuf = (float*)(base + 1024);
    float* xagg = (float*)(base + 1024 + (size_t)N * KNN_ * sizeof(float));
    float* x2   = (float*)(base + 1024 + (size_t)N * KNN_ * sizeof(float) + (size_t)N * CI * sizeof(float));
    float* ybuf = xagg;

    hipMemsetAsync(stats, 0, 6 * CI * sizeof(double), stream);

    const int B = 256;
    const int gridN = (N + B - 1) / B;
    k1_stats  <<<2048, B, 0, stream>>>(points, feature, index, W1, stats, N);
    k3_attn   <<<gridN, B, 0, stream>>>(points, feature, index, W1, g1, b1, stats, wbuf, xagg, N);
    k4_prop   <<<2048, B, 0, stream>>>(index, wbuf, xagg, x2, stats + 2 * CI, N);
    k6_refine1<<<2048, B, 0, stream>>>(x2, feature, g2, b2, Wr1, br1, stats + 2 * CI, ybuf, stats + 4 * CI, N);
    k8_out    <<<gridN, B, 0, stream>>>(ybuf, g3, b3, Wr2, br2, stats + 4 * CI, out, N);
}

// Round 3
// 3068.515 us; speedup vs baseline: 3.1910x; 3.1910x over previous
//
#include <hip/hip_runtime.h>

// Attention2: point-cloud attention, N=1M, KNN=9, C_in=C_inner=20, REPEAT=2.
// All data fp32. Three training-mode BNs require global stats passes.
// R3: the live set of k1/k3/k4 is ~75-110 floats. Round-1 (full unroll, 256
// VGPR) and round-2 (launch_bounds(256,4) -> compiler clamped to 64 VGPR)
// both spilled to scratch (GBs of FETCH/WRITE). Fix: unroll-1 neighbor loop
// AND unconstrained allocator (plain __launch_bounds__(256)) so the ~110-reg
// live set stays in registers. Do NOT add a min-waves arg here: the compiler
// over-clamps (observed 64 VGPR at (256,4) -> 12 GB spill traffic).

constexpr int KNN_ = 9;
constexpr int CI   = 20;   // in/inner channels
constexpr int CC   = 23;   // CI + 3 (xyz)
constexpr int CAT  = 40;   // CI + CI
constexpr float EPS = 1e-5f;

// ---- block-wide reduce of CNT float partials into f64 global accumulators ----
template <int CNT>
__device__ inline void block_reduce_add(float (&v)[CNT], double* __restrict__ dst,
                                        float* __restrict__ lds /*4*CNT floats*/) {
    const int lane = threadIdx.x & 63;
    const int wid  = threadIdx.x >> 6;
#pragma unroll
    for (int i = 0; i < CNT; ++i) {
        float x = v[i];
#pragma unroll
        for (int off = 32; off > 0; off >>= 1) x += __shfl_down(x, off);
        if (lane == 0) lds[wid * CNT + i] = x;
    }
    __syncthreads();
    if (threadIdx.x < CNT) {
        float x = lds[threadIdx.x] + lds[CNT + threadIdx.x] +
                  lds[2 * CNT + threadIdx.x] + lds[3 * CNT + threadIdx.x];
        atomicAdd(dst + threadIdx.x, (double)x);
    }
}

__device__ inline void load_row20(const float* __restrict__ p, float (&v)[CC]) {
    const float4* f = reinterpret_cast<const float4*>(p);
    const float4 f0 = f[0], f1 = f[1], f2 = f[2], f3 = f[3], f4 = f[4];
    v[0]=f0.x; v[1]=f0.y; v[2]=f0.z; v[3]=f0.w;
    v[4]=f1.x; v[5]=f1.y; v[6]=f1.z; v[7]=f1.w;
    v[8]=f2.x; v[9]=f2.y; v[10]=f2.z; v[11]=f2.w;
    v[12]=f3.x; v[13]=f3.y; v[14]=f3.z; v[15]=f3.w;
    v[16]=f4.x; v[17]=f4.y; v[18]=f4.z; v[19]=f4.w;
}

// ---- K1: per-channel sum/sumsq of conv1 output over all (n,k) — BN1 stats ----
__global__ __launch_bounds__(256) void k1_stats(
    const float* __restrict__ points, const float* __restrict__ feature,
    const int* __restrict__ index, const float* __restrict__ W1,
    double* __restrict__ stats, int N)
{
    __shared__ float Ws[CI * CC];
    __shared__ float red[4 * 2 * CI];
    for (int i = threadIdx.x; i < CI * CC; i += 256) Ws[i] = W1[i];
    __syncthreads();

    float acc[2 * CI];
#pragma unroll
    for (int i = 0; i < 2 * CI; ++i) acc[i] = 0.f;

    const int total = N * KNN_;
#pragma unroll 1
    for (int pid = blockIdx.x * 256 + threadIdx.x; pid < total; pid += gridDim.x * 256) {
        const int n = pid / KNN_;
        const int j = index[pid];
        float in[CC];
        load_row20(feature + (size_t)j * CI, in);
        in[20] = points[3*j+0] - points[3*n+0];
        in[21] = points[3*j+1] - points[3*n+1];
        in[22] = points[3*j+2] - points[3*n+2];
#pragma unroll
        for (int o = 0; o < CI; ++o) {
            float y = 0.f;
#pragma unroll
            for (int c = 0; c < CC; ++c) y = fmaf(Ws[o * CC + c], in[c], y);
            acc[o] += y;
            acc[CI + o] = fmaf(y, y, acc[CI + o]);
        }
    }
    __syncthreads();
    block_reduce_add<2 * CI>(acc, stats, red);
}

// ---- K3: recompute conv1, apply BN1, attention weights w, aggregate xagg ----
__global__ __launch_bounds__(256) void k3_attn(
    const float* __restrict__ points, const float* __restrict__ feature,
    const int* __restrict__ index, const float* __restrict__ W1,
    const float* __restrict__ g1, const float* __restrict__ b1,
    const double* __restrict__ stats,
    float* __restrict__ wbuf, float* __restrict__ xagg, int N)
{
    __shared__ float Ws[CI * CC];
    __shared__ float sc[CI], sh[CI];
    for (int i = threadIdx.x; i < CI * CC; i += 256) Ws[i] = W1[i];
    if (threadIdx.x < CI) {
        const double M = (double)N * KNN_;
        const double mean = stats[threadIdx.x] / M;
        const double var  = stats[CI + threadIdx.x] / M - mean * mean;
        const float s = g1[threadIdx.x] * rsqrtf((float)var + EPS);
        sc[threadIdx.x] = s;
        sh[threadIdx.x] = b1[threadIdx.x] - (float)mean * s;
    }
    __syncthreads();

    const int n = blockIdx.x * 256 + threadIdx.x;
    if (n >= N) return;

    int idx[KNN_];
#pragma unroll
    for (int k = 0; k < KNN_; ++k) idx[k] = index[n * KNN_ + k];

    const float pnx = points[3*n], pny = points[3*n+1], pnz = points[3*n+2];
    float x0[CI], accv[CI];
#pragma unroll
    for (int o = 0; o < CI; ++o) accv[o] = 0.f;

#pragma unroll 1
    for (int k = 0; k < KNN_; ++k) {
        const int j = idx[k];
        float in[CC];
        load_row20(feature + (size_t)j * CI, in);
        in[20] = points[3*j+0] - pnx;
        in[21] = points[3*j+1] - pny;
        in[22] = points[3*j+2] - pnz;
        float xk[CI];
#pragma unroll
        for (int o = 0; o < CI; ++o) {
            float y = 0.f;
#pragma unroll
            for (int c = 0; c < CC; ++c) y = fmaf(Ws[o * CC + c], in[c], y);
            xk[o] = fmaf(y, sc[o], sh[o]);
        }
        if (k == 0) {
#pragma unroll
            for (int o = 0; o < CI; ++o) x0[o] = xk[o];
        }
        float w = 0.f;
#pragma unroll
        for (int o = 0; o < CI; ++o) w = fmaf(xk[o], x0[o], w);
        wbuf[n * KNN_ + k] = w;
#pragma unroll
        for (int o = 0; o < CI; ++o) accv[o] = fmaf(xk[o], w, accv[o]);
    }
    float4* xo = reinterpret_cast<float4*>(xagg + (size_t)n * CI);
    xo[0] = make_float4(accv[0],  accv[1],  accv[2],  accv[3]);
    xo[1] = make_float4(accv[4],  accv[5],  accv[6],  accv[7]);
    xo[2] = make_float4(accv[8],  accv[9],  accv[10], accv[11]);
    xo[3] = make_float4(accv[12], accv[13], accv[14], accv[15]);
    xo[4] = make_float4(accv[16], accv[17], accv[18], accv[19]);
}

// ---- K4: x2[n] = sum_k xagg[idx[n,k]]*w[n,k]; fused BN2 stats ----
__global__ __launch_bounds__(256) void k4_prop(
    const int* __restrict__ index, const float* __restrict__ wbuf,
    const float* __restrict__ xagg, float* __restrict__ x2,
    double* __restrict__ stats2, int N)
{
    __shared__ float red[4 * 2 * CI];
    float st[2 * CI];
#pragma unroll
    for (int i = 0; i < 2 * CI; ++i) st[i] = 0.f;

#pragma unroll 1
    for (int n = blockIdx.x * 256 + threadIdx.x; n < N; n += gridDim.x * 256) {
        int idx[KNN_];
        float wk[KNN_];
#pragma unroll
        for (int k = 0; k < KNN_; ++k) idx[k] = index[n * KNN_ + k];
#pragma unroll
        for (int k = 0; k < KNN_; ++k) wk[k] = wbuf[n * KNN_ + k];

        float accv[CI];
#pragma unroll
        for (int o = 0; o < CI; ++o) accv[o] = 0.f;
#pragma unroll 1
        for (int k = 0; k < KNN_; ++k) {
            const int j = idx[k];
            const float w = wk[k];
            float gv[CC];
            load_row20(xagg + (size_t)j * CI, gv);
#pragma unroll
            for (int o = 0; o < CI; ++o) accv[o] = fmaf(gv[o], w, accv[o]);
        }
        float4* xo = reinterpret_cast<float4*>(x2 + (size_t)n * CI);
        xo[0] = make_float4(accv[0],  accv[1],  accv[2],  accv[3]);
        xo[1] = make_float4(accv[4],  accv[5],  accv[6],  accv[7]);
        xo[2] = make_float4(accv[8],  accv[9],  accv[10], accv[11]);
        xo[3] = make_float4(accv[12], accv[13], accv[14], accv[15]);
        xo[4] = make_float4(accv[16], accv[17], accv[18], accv[19]);
#pragma unroll
        for (int o = 0; o < CI; ++o) {
            st[o] += accv[o];
            st[CI + o] = fmaf(accv[o], accv[o], st[CI + o]);
        }
    }
    __syncthreads();
    block_reduce_add<2 * CI>(st, stats2, red);
}

// ---- K6: h=relu(bn2(x2)); cat=[h,feature]; y=Wr1@cat+br1; fused BN3 stats ----
__global__ __launch_bounds__(256) void k6_refine1(
    const float* __restrict__ x2, const float* __restrict__ feature,
    const float* __restrict__ g2, const float* __restrict__ b2,
    const float* __restrict__ Wr1, const float* __restrict__ br1,
    const double* __restrict__ stats2,
    float* __restrict__ ybuf, double* __restrict__ stats3, int N)
{
    __shared__ float Ws[CI * CAT];
    __shared__ float sc[CI], sh[CI];
    __shared__ float red[4 * 2 * CI];
    for (int i = threadIdx.x; i < CI * CAT; i += 256) Ws[i] = Wr1[i];
    if (threadIdx.x < CI) {
        const double M = (double)N;
        const double mean = stats2[threadIdx.x] / M;
        const double var  = stats2[CI + threadIdx.x] / M - mean * mean;
        const float s = g2[threadIdx.x] * rsqrtf((float)var + EPS);
        sc[threadIdx.x] = s;
        sh[threadIdx.x] = b2[threadIdx.x] - (float)mean * s;
    }
    __syncthreads();

    float st[2 * CI];
#pragma unroll
    for (int i = 0; i < 2 * CI; ++i) st[i] = 0.f;

#pragma unroll 1
    for (int n = blockIdx.x * 256 + threadIdx.x; n < N; n += gridDim.x * 256) {
        float cat[CAT];
        const float4* xi = reinterpret_cast<const float4*>(x2 + (size_t)n * CI);
#pragma unroll
        for (int q = 0; q < 5; ++q) {
            const float4 v = xi[q];
            cat[4*q+0] = fmaxf(fmaf(v.x, sc[4*q+0], sh[4*q+0]), 0.f);
            cat[4*q+1] = fmaxf(fmaf(v.y, sc[4*q+1], sh[4*q+1]), 0.f);
            cat[4*q+2] = fmaxf(fmaf(v.z, sc[4*q+2], sh[4*q+2]), 0.f);
            cat[4*q+3] = fmaxf(fmaf(v.w, sc[4*q+3], sh[4*q+3]), 0.f);
        }
        const float4* fi = reinterpret_cast<const float4*>(feature + (size_t)n * CI);
#pragma unroll
        for (int q = 0; q < 5; ++q) {
            const float4 v = fi[q];
            cat[CI+4*q+0] = v.x; cat[CI+4*q+1] = v.y;
            cat[CI+4*q+2] = v.z; cat[CI+4*q+3] = v.w;
        }
        float yv[CI];
#pragma unroll
        for (int o = 0; o < CI; ++o) {
            float y = br1[o];
#pragma unroll
            for (int c = 0; c < CAT; ++c) y = fmaf(Ws[o * CAT + c], cat[c], y);
            yv[o] = y;
            st[o] += y;
            st[CI + o] = fmaf(y, y, st[CI + o]);
        }
        float4* yo = reinterpret_cast<float4*>(ybuf + (size_t)n * CI);
        yo[0] = make_float4(yv[0],  yv[1],  yv[2],  yv[3]);
        yo[1] = make_float4(yv[4],  yv[5],  yv[6],  yv[7]);
        yo[2] = make_float4(yv[8],  yv[9],  yv[10], yv[11]);
        yo[3] = make_float4(yv[12], yv[13], yv[14], yv[15]);
        yo[4] = make_float4(yv[16], yv[17], yv[18], yv[19]);
    }
    __syncthreads();
    block_reduce_add<2 * CI>(st, stats3, red);
}

// ---- K8: out = relu(bn3(y)) @ Wr2.T + br2 ----
__global__ __launch_bounds__(256) void k8_out(
    const float* __restrict__ ybuf,
    const float* __restrict__ g3, const float* __restrict__ b3,
    const float* __restrict__ Wr2, const float* __restrict__ br2,
    const double* __restrict__ stats3, float* __restrict__ out, int N)
{
    __shared__ float Ws[CI * CI];
    __shared__ float sc[CI], sh[CI];
    for (int i = threadIdx.x; i < CI * CI; i += 256) Ws[i] = Wr2[i];
    if (threadIdx.x < CI) {
        const double M = (double)N;
        const double mean = stats3[threadIdx.x] / M;
        const double var  = stats3[CI + threadIdx.x] / M - mean * mean;
        const float s = g3[threadIdx.x] * rsqrtf((float)var + EPS);
        sc[threadIdx.x] = s;
        sh[threadIdx.x] = b3[threadIdx.x] - (float)mean * s;
    }
    __syncthreads();

    const int n = blockIdx.x * 256 + threadIdx.x;
    if (n >= N) return;

    float z[CI];
    const float4* yi = reinterpret_cast<const float4*>(ybuf + (size_t)n * CI);
#pragma unroll
    for (int q = 0; q < 5; ++q) {
        const float4 v = yi[q];
        z[4*q+0] = fmaxf(fmaf(v.x, sc[4*q+0], sh[4*q+0]), 0.f);
        z[4*q+1] = fmaxf(fmaf(v.y, sc[4*q+1], sh[4*q+1]), 0.f);
        z[4*q+2] = fmaxf(fmaf(v.z, sc[4*q+2], sh[4*q+2]), 0.f);
        z[4*q+3] = fmaxf(fmaf(v.w, sc[4*q+3], sh[4*q+3]), 0.f);
    }
    float ov[CI];
#pragma unroll
    for (int o = 0; o < CI; ++o) {
        float y = br2[o];
#pragma unroll
        for (int c = 0; c < CI; ++c) y = fmaf(Ws[o * CI + c], z[c], y);
        ov[o] = y;
    }
    float4* oo = reinterpret_cast<float4*>(out + (size_t)n * CI);
    oo[0] = make_float4(ov[0],  ov[1],  ov[2],  ov[3]);
    oo[1] = make_float4(ov[4],  ov[5],  ov[6],  ov[7]);
    oo[2] = make_float4(ov[8],  ov[9],  ov[10], ov[11]);
    oo[3] = make_float4(ov[12], ov[13], ov[14], ov[15]);
    oo[4] = make_float4(ov[16], ov[17], ov[18], ov[19]);
}

extern "C" void kernel_launch(void* const* d_in, const int* in_sizes, int n_in,
                              void* d_out, int out_size, void* d_ws, size_t ws_size,
                              hipStream_t stream) {
    const float* points  = (const float*)d_in[0];
    const float* feature = (const float*)d_in[1];
    const int*   index   = (const int*)  d_in[2];
    const float* W1      = (const float*)d_in[3];
    const float* g1      = (const float*)d_in[4];
    const float* b1      = (const float*)d_in[5];
    const float* g2      = (const float*)d_in[6];
    const float* b2      = (const float*)d_in[7];
    const float* Wr1     = (const float*)d_in[8];
    const float* br1     = (const float*)d_in[9];
    const float* g3      = (const float*)d_in[10];
    const float* b3      = (const float*)d_in[11];
    const float* Wr2     = (const float*)d_in[12];
    const float* br2     = (const float*)d_in[13];
    const int N = in_sizes[0] / 3;
    float* out = (float*)d_out;

    // workspace layout: [stats: 120 doubles, padded to 1KB][w: N*9 f32][xagg: N*20 f32][x2: N*20 f32]
    // ybuf aliases xagg (dead after k4). Total ~196 MB.
    double* stats = (double*)d_ws;
    char* base = (char*)d_ws;
    float* wbuf = (float*)(base + 1024);
    float* xagg = (float*)(base + 1024 + (size_t)N * KNN_ * sizeof(float));
    float* x2   = (float*)(base + 1024 + (size_t)N * KNN_ * sizeof(float) + (size_t)N * CI * sizeof(float));
    float* ybuf = xagg;

    hipMemsetAsync(stats, 0, 6 * CI * sizeof(double), stream);

    const int B = 256;
    const int gridN = (N + B - 1) / B;
    k1_stats  <<<2048, B, 0, stream>>>(points, feature, index, W1, stats, N);
    k3_attn   <<<gridN, B, 0, stream>>>(points, feature, index, W1, g1, b1, stats, wbuf, xagg, N);
    k4_prop   <<<2048, B, 0, stream>>>(index, wbuf, xagg, x2, stats + 2 * CI, N);
    k6_refine1<<<2048, B, 0, stream>>>(x2, feature, g2, b2, Wr1, br1, stats + 2 * CI, ybuf, stats + 4 * CI, N);
    k8_out    <<<gridN, B, 0, stream>>>(ybuf, g3, b3, Wr2, br2, stats + 4 * CI, out, N);
}

// Round 4
// 1333.682 us; speedup vs baseline: 7.3419x; 2.3008x over previous
//
#include <hip/hip_runtime.h>

// Attention2: point-cloud attention, N=1M, KNN=9, C_in=C_inner=20, REPEAT=2.
// R4 key restructuring: conv1 is affine, so
//   y[n,k] = W·[feat[j], p[j]-p[n]] = u[j] - v[n],
//   u[j] = W_f·feat[j] + W_x·p[j]  (per-point, precomputed once, k0)
//   v[n] = W_x·p[n]                (60 FMA, recomputed on the fly)
// Gather passes (k1 stats, k3 attention, k4 propagate) become light:
// load one row + ~60 FMA instead of 460-FMA conv per gather.
// Register discipline: live sets ~115 floats; __launch_bounds__(256,3)
// (~168-reg cap) — NOT (256,4), which made the compiler clamp to 64 regs and
// spill 12 GB (R2); NOT unconstrained, which greedily took 256 and still
// spilled (R3).
// Gather rows padded to 128 B (1 cache line) when ws_size permits.

constexpr int KNN_ = 9;
constexpr int CI   = 20;
constexpr int CC   = 23;
constexpr int CAT  = 40;
constexpr float EPS = 1e-5f;

template <int CNT>
__device__ inline void block_reduce_add(float (&v)[CNT], double* __restrict__ dst,
                                        float* __restrict__ lds /*4*CNT floats*/) {
    const int lane = threadIdx.x & 63;
    const int wid  = threadIdx.x >> 6;
#pragma unroll
    for (int i = 0; i < CNT; ++i) {
        float x = v[i];
#pragma unroll
        for (int off = 32; off > 0; off >>= 1) x += __shfl_down(x, off);
        if (lane == 0) lds[wid * CNT + i] = x;
    }
    __syncthreads();
    if (threadIdx.x < CNT) {
        float x = lds[threadIdx.x] + lds[CNT + threadIdx.x] +
                  lds[2 * CNT + threadIdx.x] + lds[3 * CNT + threadIdx.x];
        atomicAdd(dst + threadIdx.x, (double)x);
    }
}

__device__ inline void loadrow20(const float* __restrict__ p, float (&v)[CI]) {
    const float4* q = reinterpret_cast<const float4*>(p);
    const float4 a = q[0], b = q[1], c = q[2], d = q[3], e = q[4];
    v[0]=a.x; v[1]=a.y; v[2]=a.z; v[3]=a.w;
    v[4]=b.x; v[5]=b.y; v[6]=b.z; v[7]=b.w;
    v[8]=c.x; v[9]=c.y; v[10]=c.z; v[11]=c.w;
    v[12]=d.x; v[13]=d.y; v[14]=d.z; v[15]=d.w;
    v[16]=e.x; v[17]=e.y; v[18]=e.z; v[19]=e.w;
}

__device__ inline void storerow20(float* __restrict__ p, const float (&v)[CI]) {
    float4* q = reinterpret_cast<float4*>(p);
    q[0] = make_float4(v[0],  v[1],  v[2],  v[3]);
    q[1] = make_float4(v[4],  v[5],  v[6],  v[7]);
    q[2] = make_float4(v[8],  v[9],  v[10], v[11]);
    q[3] = make_float4(v[12], v[13], v[14], v[15]);
    q[4] = make_float4(v[16], v[17], v[18], v[19]);
}

// ---- K0: u[n] = W_f·feat[n] + W_x·p[n] (streamed, once per point) ----
__global__ __launch_bounds__(256) void k0_uv(
    const float* __restrict__ points, const float* __restrict__ feature,
    const float* __restrict__ W1, float* __restrict__ u, int us, int N)
{
    __shared__ float Ws[CI * CC];
    for (int i = threadIdx.x; i < CI * CC; i += 256) Ws[i] = W1[i];
    __syncthreads();
    const int n = blockIdx.x * 256 + threadIdx.x;
    if (n >= N) return;
    float in[CI];
    loadrow20(feature + (size_t)n * CI, in);
    const float px = points[3*n], py = points[3*n+1], pz = points[3*n+2];
    float uo[CI];
#pragma unroll
    for (int o = 0; o < CI; ++o) {
        float y = Ws[o*CC+20] * px;
        y = fmaf(Ws[o*CC+21], py, y);
        y = fmaf(Ws[o*CC+22], pz, y);
#pragma unroll
        for (int c = 0; c < CI; ++c) y = fmaf(Ws[o*CC+c], in[c], y);
        uo[o] = y;
    }
    storerow20(u + (size_t)n * us, uo);
}

// ---- K1: BN1 stats of y = u[idx[n,k]] - v[n] over all 9M pairs ----
__global__ __launch_bounds__(256, 3) void k1_stats(
    const float* __restrict__ points, const int* __restrict__ index,
    const float* __restrict__ W1, const float* __restrict__ u, int us,
    double* __restrict__ stats, int N)
{
    __shared__ float Ws[CI * CC];
    __shared__ float red[4 * 2 * CI];
    for (int i = threadIdx.x; i < CI * CC; i += 256) Ws[i] = W1[i];
    __syncthreads();

    float acc[2 * CI];
#pragma unroll
    for (int i = 0; i < 2 * CI; ++i) acc[i] = 0.f;

#pragma unroll 1
    for (int n = blockIdx.x * 256 + threadIdx.x; n < N; n += gridDim.x * 256) {
        const float px = points[3*n], py = points[3*n+1], pz = points[3*n+2];
        float v[CI];
#pragma unroll
        for (int o = 0; o < CI; ++o) {
            float t = Ws[o*CC+20] * px;
            t = fmaf(Ws[o*CC+21], py, t);
            v[o] = fmaf(Ws[o*CC+22], pz, t);
        }
        int idx[KNN_];
#pragma unroll
        for (int k = 0; k < KNN_; ++k) idx[k] = index[n * KNN_ + k];

#pragma unroll 1
        for (int t = 0; t < 4; ++t) {
            float ra[CI], rb[CI];
            loadrow20(u + (size_t)idx[2*t]   * us, ra);
            loadrow20(u + (size_t)idx[2*t+1] * us, rb);
#pragma unroll
            for (int o = 0; o < CI; ++o) {
                const float d = ra[o] - v[o];
                acc[o] += d;
                acc[CI + o] = fmaf(d, d, acc[CI + o]);
            }
#pragma unroll
            for (int o = 0; o < CI; ++o) {
                const float d = rb[o] - v[o];
                acc[o] += d;
                acc[CI + o] = fmaf(d, d, acc[CI + o]);
            }
        }
        {   // k = 8 tail
            float ra[CI];
            loadrow20(u + (size_t)idx[8] * us, ra);
#pragma unroll
            for (int o = 0; o < CI; ++o) {
                const float d = ra[o] - v[o];
                acc[o] += d;
                acc[CI + o] = fmaf(d, d, acc[CI + o]);
            }
        }
    }
    __syncthreads();
    block_reduce_add<2 * CI>(acc, stats, red);
}

// ---- K3: xk = u[j]*sc - v2[n]; w_k = xk·x0; xagg = Σ xk w_k ----
__global__ __launch_bounds__(256, 3) void k3_attn(
    const float* __restrict__ points, const int* __restrict__ index,
    const float* __restrict__ W1, const float* __restrict__ g1,
    const float* __restrict__ b1, const double* __restrict__ stats,
    const float* __restrict__ u, int us,
    float* __restrict__ wbuf, float* __restrict__ xagg, int as, int N)
{
    __shared__ float Ws[CI * CC];
    __shared__ float sc[CI], sh[CI];
    for (int i = threadIdx.x; i < CI * CC; i += 256) Ws[i] = W1[i];
    if (threadIdx.x < CI) {
        const double M = (double)N * KNN_;
        const double mean = stats[threadIdx.x] / M;
        const double var  = stats[CI + threadIdx.x] / M - mean * mean;
        const float s = g1[threadIdx.x] * rsqrtf((float)var + EPS);
        sc[threadIdx.x] = s;
        sh[threadIdx.x] = b1[threadIdx.x] - (float)mean * s;
    }
    __syncthreads();

    const int n = blockIdx.x * 256 + threadIdx.x;
    if (n >= N) return;

    const float px = points[3*n], py = points[3*n+1], pz = points[3*n+2];
    float v2[CI];   // v*sc - sh, so xk = u*sc - v2
#pragma unroll
    for (int o = 0; o < CI; ++o) {
        float t = Ws[o*CC+20] * px;
        t = fmaf(Ws[o*CC+21], py, t);
        t = fmaf(Ws[o*CC+22], pz, t);
        v2[o] = fmaf(t, sc[o], -sh[o]);
    }
    int idx[KNN_];
#pragma unroll
    for (int k = 0; k < KNN_; ++k) idx[k] = index[n * KNN_ + k];

    float x0[CI], accv[CI];
    {   // k = 0
        float r[CI];
        loadrow20(u + (size_t)idx[0] * us, r);
        float w0 = 0.f;
#pragma unroll
        for (int o = 0; o < CI; ++o) x0[o] = fmaf(r[o], sc[o], -v2[o]);
#pragma unroll
        for (int o = 0; o < CI; ++o) w0 = fmaf(x0[o], x0[o], w0);
        wbuf[n * KNN_] = w0;
#pragma unroll
        for (int o = 0; o < CI; ++o) accv[o] = x0[o] * w0;
    }
#pragma unroll 1
    for (int t = 0; t < 4; ++t) {
        const int ka = 1 + 2*t, kb = 2 + 2*t;
        float ra[CI], rb[CI];
        loadrow20(u + (size_t)idx[ka] * us, ra);
        loadrow20(u + (size_t)idx[kb] * us, rb);
        float wa = 0.f, wb = 0.f;
#pragma unroll
        for (int o = 0; o < CI; ++o) {
            ra[o] = fmaf(ra[o], sc[o], -v2[o]);
            wa = fmaf(ra[o], x0[o], wa);
        }
#pragma unroll
        for (int o = 0; o < CI; ++o) {
            rb[o] = fmaf(rb[o], sc[o], -v2[o]);
            wb = fmaf(rb[o], x0[o], wb);
        }
        wbuf[n * KNN_ + ka] = wa;
        wbuf[n * KNN_ + kb] = wb;
#pragma unroll
        for (int o = 0; o < CI; ++o) accv[o] = fmaf(ra[o], wa, accv[o]);
#pragma unroll
        for (int o = 0; o < CI; ++o) accv[o] = fmaf(rb[o], wb, accv[o]);
    }
    storerow20(xagg + (size_t)n * as, accv);
}

// ---- K4: x2[n] = Σ_k xagg[idx[n,k]]·w[n,k]; fused BN2 stats ----
__global__ __launch_bounds__(256, 3) void k4_prop(
    const int* __restrict__ index, const float* __restrict__ wbuf,
    const float* __restrict__ xagg, int as, float* __restrict__ x2,
    double* __restrict__ stats2, int N)
{
    __shared__ float red[4 * 2 * CI];
    float st[2 * CI];
#pragma unroll
    for (int i = 0; i < 2 * CI; ++i) st[i] = 0.f;

#pragma unroll 1
    for (int n = blockIdx.x * 256 + threadIdx.x; n < N; n += gridDim.x * 256) {
        int idx[KNN_];
        float wk[KNN_];
#pragma unroll
        for (int k = 0; k < KNN_; ++k) idx[k] = index[n * KNN_ + k];
#pragma unroll
        for (int k = 0; k < KNN_; ++k) wk[k] = wbuf[n * KNN_ + k];

        float accv[CI];
        {
            float r[CI];
            loadrow20(xagg + (size_t)idx[0] * as, r);
#pragma unroll
            for (int o = 0; o < CI; ++o) accv[o] = r[o] * wk[0];
        }
#pragma unroll 1
        for (int t = 0; t < 4; ++t) {
            const int ka = 1 + 2*t, kb = 2 + 2*t;
            float ra[CI], rb[CI];
            loadrow20(xagg + (size_t)idx[ka] * as, ra);
            loadrow20(xagg + (size_t)idx[kb] * as, rb);
#pragma unroll
            for (int o = 0; o < CI; ++o) accv[o] = fmaf(ra[o], wk[ka], accv[o]);
#pragma unroll
            for (int o = 0; o < CI; ++o) accv[o] = fmaf(rb[o], wk[kb], accv[o]);
        }
        storerow20(x2 + (size_t)n * CI, accv);
#pragma unroll
        for (int o = 0; o < CI; ++o) {
            st[o] += accv[o];
            st[CI + o] = fmaf(accv[o], accv[o], st[CI + o]);
        }
    }
    __syncthreads();
    block_reduce_add<2 * CI>(st, stats2, red);
}

// ---- K6: h=relu(bn2(x2)); cat=[h,feature]; y=Wr1@cat+br1; BN3 stats ----
__global__ __launch_bounds__(256) void k6_refine1(
    const float* __restrict__ x2, const float* __restrict__ feature,
    const float* __restrict__ g2, const float* __restrict__ b2,
    const float* __restrict__ Wr1, const float* __restrict__ br1,
    const double* __restrict__ stats2,
    float* __restrict__ ybuf, double* __restrict__ stats3, int N)
{
    __shared__ float Ws[CI * CAT];
    __shared__ float sc[CI], sh[CI];
    __shared__ float red[4 * 2 * CI];
    for (int i = threadIdx.x; i < CI * CAT; i += 256) Ws[i] = Wr1[i];
    if (threadIdx.x < CI) {
        const double M = (double)N;
        const double mean = stats2[threadIdx.x] / M;
        const double var  = stats2[CI + threadIdx.x] / M - mean * mean;
        const float s = g2[threadIdx.x] * rsqrtf((float)var + EPS);
        sc[threadIdx.x] = s;
        sh[threadIdx.x] = b2[threadIdx.x] - (float)mean * s;
    }
    __syncthreads();

    float st[2 * CI];
#pragma unroll
    for (int i = 0; i < 2 * CI; ++i) st[i] = 0.f;

#pragma unroll 1
    for (int n = blockIdx.x * 256 + threadIdx.x; n < N; n += gridDim.x * 256) {
        float cat[CAT];
        {
            float xi[CI];
            loadrow20(x2 + (size_t)n * CI, xi);
#pragma unroll
            for (int o = 0; o < CI; ++o)
                cat[o] = fmaxf(fmaf(xi[o], sc[o], sh[o]), 0.f);
        }
        {
            float fi[CI];
            loadrow20(feature + (size_t)n * CI, fi);
#pragma unroll
            for (int o = 0; o < CI; ++o) cat[CI + o] = fi[o];
        }
        float yv[CI];
#pragma unroll
        for (int o = 0; o < CI; ++o) {
            float y = br1[o];
#pragma unroll
            for (int c = 0; c < CAT; ++c) y = fmaf(Ws[o * CAT + c], cat[c], y);
            yv[o] = y;
            st[o] += y;
            st[CI + o] = fmaf(y, y, st[CI + o]);
        }
        storerow20(ybuf + (size_t)n * CI, yv);
    }
    __syncthreads();
    block_reduce_add<2 * CI>(st, stats3, red);
}

// ---- K8: out = relu(bn3(y)) @ Wr2.T + br2 ----
__global__ __launch_bounds__(256) void k8_out(
    const float* __restrict__ ybuf,
    const float* __restrict__ g3, const float* __restrict__ b3,
    const float* __restrict__ Wr2, const float* __restrict__ br2,
    const double* __restrict__ stats3, float* __restrict__ out, int N)
{
    __shared__ float Ws[CI * CI];
    __shared__ float sc[CI], sh[CI];
    for (int i = threadIdx.x; i < CI * CI; i += 256) Ws[i] = Wr2[i];
    if (threadIdx.x < CI) {
        const double M = (double)N;
        const double mean = stats3[threadIdx.x] / M;
        const double var  = stats3[CI + threadIdx.x] / M - mean * mean;
        const float s = g3[threadIdx.x] * rsqrtf((float)var + EPS);
        sc[threadIdx.x] = s;
        sh[threadIdx.x] = b3[threadIdx.x] - (float)mean * s;
    }
    __syncthreads();

    const int n = blockIdx.x * 256 + threadIdx.x;
    if (n >= N) return;

    float z[CI];
    {
        float yi[CI];
        loadrow20(ybuf + (size_t)n * CI, yi);
#pragma unroll
        for (int o = 0; o < CI; ++o)
            z[o] = fmaxf(fmaf(yi[o], sc[o], sh[o]), 0.f);
    }
    float ov[CI];
#pragma unroll
    for (int o = 0; o < CI; ++o) {
        float y = br2[o];
#pragma unroll
        for (int c = 0; c < CI; ++c) y = fmaf(Ws[o * CI + c], z[c], y);
        ov[o] = y;
    }
    storerow20(out + (size_t)n * CI, ov);
}

extern "C" void kernel_launch(void* const* d_in, const int* in_sizes, int n_in,
                              void* d_out, int out_size, void* d_ws, size_t ws_size,
                              hipStream_t stream) {
    const float* points  = (const float*)d_in[0];
    const float* feature = (const float*)d_in[1];
    const int*   index   = (const int*)  d_in[2];
    const float* W1      = (const float*)d_in[3];
    const float* g1      = (const float*)d_in[4];
    const float* b1      = (const float*)d_in[5];
    const float* g2      = (const float*)d_in[6];
    const float* b2      = (const float*)d_in[7];
    const float* Wr1     = (const float*)d_in[8];
    const float* br1     = (const float*)d_in[9];
    const float* g3      = (const float*)d_in[10];
    const float* b3      = (const float*)d_in[11];
    const float* Wr2     = (const float*)d_in[12];
    const float* br2     = (const float*)d_in[13];
    const int N = in_sizes[0] / 3;
    float* out = (float*)d_out;

    // ws layout: [stats 1KB][wbuf N*9][u N*us][xagg N*as]; x2 aliases u
    // (dead after k3), ybuf aliases xagg (dead after k4).
    // Padded rows (us=as=32 -> 128B = 1 cache line/gather) if ws allows,
    // else proven-safe compact layout (us=as=20, 196 MB total).
    const size_t needPad = 1024 + (size_t)N * KNN_ * 4 + 2 * (size_t)N * 32 * 4;
    const bool pad = ws_size >= needPad;
    const int us = pad ? 32 : CI;
    const int as = pad ? 32 : CI;

    double* stats = (double*)d_ws;
    char* base = (char*)d_ws;
    size_t off = 1024;
    float* wbuf = (float*)(base + off); off += (size_t)N * KNN_ * 4;
    float* u    = (float*)(base + off); off += (size_t)N * us * 4;
    float* xagg = (float*)(base + off);
    float* x2   = u;     // alias: u dead after k3
    float* ybuf = xagg;  // alias: xagg dead after k4

    hipMemsetAsync(stats, 0, 6 * CI * sizeof(double), stream);

    const int B = 256;
    const int gridN = (N + B - 1) / B;
    k0_uv     <<<gridN, B, 0, stream>>>(points, feature, W1, u, us, N);
    k1_stats  <<<2048, B, 0, stream>>>(points, index, W1, u, us, stats, N);
    k3_attn   <<<gridN, B, 0, stream>>>(points, index, W1, g1, b1, stats, u, us, wbuf, xagg, as, N);
    k4_prop   <<<2048, B, 0, stream>>>(index, wbuf, xagg, as, x2, stats + 2 * CI, N);
    k6_refine1<<<2048, B, 0, stream>>>(x2, feature, g2, b2, Wr1, br1, stats + 2 * CI, ybuf, stats + 4 * CI, N);
    k8_out    <<<gridN, B, 0, stream>>>(ybuf, g3, b3, Wr2, br2, stats + 4 * CI, out, N);
}